// Round 2
// baseline (7078.200 us; speedup 1.0000x reference)
//
#include <hip/hip_runtime.h>
#include <math.h>

#define JITTER 0.001f

// ---- workspace layout (float offsets) ----
enum {
  OFF_S     = 0,            // 64x64 spatial kernel
  OFF_T     = 4096,         // 100x100 temporal kernel
  OFF_KS    = 14096,        // 64x64 test-spatial  [Ms,Ns]
  OFF_KT    = 18192,        // 100x100 test-temporal [Mt,Nt]
  OFF_Y     = 28192,        // 64x100 calibrated data
  OFF_EWS   = 34592,        // 64  spatial eigenvalues
  OFF_VS    = 34656,        // 64x64 spatial eigenvectors (columns)
  OFF_EWT   = 38752,        // 100 temporal eigenvalues
  OFF_VT    = 38852,        // 100x100 temporal eigenvectors (columns)
  OFF_P1    = 48852,        // 64x100 temp
  OFF_TILDE = 55252,        // 64x100 temp
  OFF_P3    = 61652,        // 64x100 temp
  OFF_ALPHA = 68052,        // 64x100 Alpha matrix
  OFF_P4    = 74452,        // 64x100 temp
  OFF_U2    = 80852,        // 100x100 (Kt@VT)^2
  OFF_W2    = 90852,        // 64x64  (Ks@VS)^2
  OFF_Z     = 94948,        // 64x100 R @ U2^T
  WS_FLOATS = 101348
};

#define NS 64
#define NT 100
#define MS 64
#define MT 100

// total build work items
#define BUILD_TOTAL (4096 + 10000 + 4096 + 10000 + 6400)

__global__ void __launch_bounds__(256) build_kernel(
    const float* __restrict__ space, const float* __restrict__ timec,
    const float* __restrict__ stData, const float* __restrict__ tspace,
    const float* __restrict__ ttime, const float* __restrict__ l_ll,
    const float* __restrict__ l_el, const float* __restrict__ l_t,
    const float* __restrict__ bias, const float* __restrict__ gain,
    float* __restrict__ ws)
{
  int idx = blockIdx.x * blockDim.x + threadIdx.x;
  if (idx >= BUILD_TOTAL) return;
  float inv_ll = expf(-l_ll[0]);
  float inv_el = expf(-l_el[0]);
  float inv_t  = expf(-l_t[0]);

  if (idx < 4096) {
    // S[i][j] = exp(-d2_ll)*exp(-d2_el) + eye*JITTER
    int i = idx >> 6, j = idx & 63;
    float dx0 = (space[i*3+0] - space[j*3+0]) * inv_ll;
    float dx1 = (space[i*3+1] - space[j*3+1]) * inv_ll;
    float dz  = (space[i*3+2] - space[j*3+2]) * inv_el;
    float v = expf(-(dx0*dx0 + dx1*dx1)) * expf(-(dz*dz));
    if (i == j) v += JITTER;
    ws[OFF_S + idx] = v;
  } else if (idx < 14096) {
    int k = idx - 4096;
    int t = k / 100, u = k % 100;
    float d = (timec[t] - timec[u]) * inv_t;
    float v = expf(-d*d);
    if (t == u) v += JITTER;
    ws[OFF_T + k] = v;
  } else if (idx < 18192) {
    int k = idx - 14096;
    int i = k >> 6, j = k & 63;   // test i, train j
    float dx0 = (tspace[i*3+0] - space[j*3+0]) * inv_ll;
    float dx1 = (tspace[i*3+1] - space[j*3+1]) * inv_ll;
    float dz  = (tspace[i*3+2] - space[j*3+2]) * inv_el;
    ws[OFF_KS + k] = expf(-(dx0*dx0 + dx1*dx1)) * expf(-(dz*dz));
  } else if (idx < 28192) {
    int k = idx - 18192;
    int j = k / 100, t = k % 100; // test j, train t
    float d = (ttime[j] - timec[t]) * inv_t;
    ws[OFF_KT + k] = expf(-d*d);
  } else {
    int k = idx - 28192;
    int s = k / 100;
    ws[OFF_Y + k] = stData[k] * gain[0] + bias[s];
  }
}

// ---- parallel-ordering two-sided Jacobi eigensolver, one block per matrix ----
// block 0: n=64 (spatial), block 1: n=100 (temporal)
__global__ void __launch_bounds__(256) jacobi_kernel(
    const float* __restrict__ Sin, float* __restrict__ wS, float* __restrict__ VSo,
    const float* __restrict__ Tin, float* __restrict__ wT, float* __restrict__ VTo)
{
  extern __shared__ float lds[];
  int n, sweeps;
  const float* Ain; float* wout; float* Vout;
  if (blockIdx.x == 0) { n = 64;  Ain = Sin; wout = wS; Vout = VSo; sweeps = 10; }
  else                 { n = 100; Ain = Tin; wout = wT; Vout = VTo; sweeps = 10; }
  const int stride = n + 1;
  const int NP = n / 2;
  float* A  = lds;
  float* V  = A + n * stride;
  float* cs = V + n * stride;
  float* sn = cs + NP;
  int*   pi = (int*)(sn + NP);
  int*   qi = pi + NP;
  const int tid = threadIdx.x;
  const int nth = blockDim.x;

  for (int idx = tid; idx < n * n; idx += nth) {
    int i = idx / n, j = idx - i * n;
    A[i * stride + j] = Ain[idx];
    V[i * stride + j] = (i == j) ? 1.0f : 0.0f;
  }
  __syncthreads();

  for (int sw = 0; sw < sweeps; ++sw) {
    for (int r = 0; r < n - 1; ++r) {
      // 1) rotation parameters per pair (round-robin tournament ordering)
      if (tid < NP) {
        int p, q;
        if (tid == 0) { p = n - 1; q = r; }
        else {
          p = (r + tid) % (n - 1);
          q = (r - tid + (n - 1)) % (n - 1);
        }
        if (p > q) { int tmp = p; p = q; q = tmp; }
        float apq = A[p * stride + q];
        float app = A[p * stride + p];
        float aqq = A[q * stride + q];
        float c, s;
        if (fabsf(apq) < 1e-36f) { c = 1.0f; s = 0.0f; }
        else {
          float theta = (aqq - app) / (2.0f * apq);
          float tt = 1.0f / (fabsf(theta) + sqrtf(1.0f + theta * theta));
          if (theta < 0.0f) tt = -tt;
          c = 1.0f / sqrtf(1.0f + tt * tt);
          s = tt * c;
        }
        cs[tid] = c; sn[tid] = s; pi[tid] = p; qi[tid] = q;
      }
      __syncthreads();
      // 2) row update: A <- J^T A   (rows p,q; contiguous in j)
      for (int w = tid; w < NP * n; w += nth) {
        int k = w / n, j = w - k * n;
        int p = pi[k], q = qi[k];
        float c = cs[k], s = sn[k];
        float ap = A[p * stride + j], aq = A[q * stride + j];
        A[p * stride + j] = c * ap - s * aq;
        A[q * stride + j] = s * ap + c * aq;
      }
      __syncthreads();
      // 3) column update: A <- A J,  V <- V J
      for (int w = tid; w < NP * n; w += nth) {
        int k = w / n, i = w - k * n;
        int p = pi[k], q = qi[k];
        float c = cs[k], s = sn[k];
        float aip = A[i * stride + p], aiq = A[i * stride + q];
        A[i * stride + p] = c * aip - s * aiq;
        A[i * stride + q] = s * aip + c * aiq;
        float vip = V[i * stride + p], viq = V[i * stride + q];
        V[i * stride + p] = c * vip - s * viq;
        V[i * stride + q] = s * vip + c * viq;
      }
      __syncthreads();
    }
  }

  for (int idx = tid; idx < n * n; idx += nth) {
    int i = idx / n, j = idx - i * n;
    Vout[idx] = V[i * stride + j];
  }
  for (int i = tid; i < n; i += nth) wout[i] = A[i * stride + i];
}

// ---- generic tiny GEMM: one thread per output element ----
// tA: 0 = A[m][k], 1 = A[k][m] (transpose), 2 = a = 1/(w1[m]*w2[k] + exp(*scal))
// tB: 0 = B[k][n], 1 = B[n][k]
// mode: 0 = acc, 1 = acc/(w1[m]*w2[n]+exp(*scal)), 2 = acc^2, 3 = exp(*scal)-acc
__global__ void __launch_bounds__(256) gemm_k(
    const float* __restrict__ A, const float* __restrict__ B,
    float* __restrict__ C, int M, int N, int K, int tA, int tB, int mode,
    const float* __restrict__ w1, const float* __restrict__ w2,
    const float* __restrict__ scal)
{
  int idx = blockIdx.x * blockDim.x + threadIdx.x;
  if (idx >= M * N) return;
  int m = idx / N, n = idx - m * N;
  float nv = (scal != nullptr) ? expf(scal[0]) : 0.0f;
  float acc = 0.0f;
  for (int k = 0; k < K; ++k) {
    float a;
    if (tA == 2)      a = 1.0f / (w1[m] * w2[k] + nv);
    else if (tA == 1) a = A[k * M + m];
    else              a = A[m * K + k];
    float b = tB ? B[n * K + k] : B[k * N + n];
    acc += a * b;
  }
  float out;
  if (mode == 1)      out = acc / (w1[m] * w2[n] + nv);
  else if (mode == 2) out = acc * acc;
  else if (mode == 3) out = nv - acc;
  else                out = acc;
  C[idx] = out;
}

extern "C" void kernel_launch(void* const* d_in, const int* in_sizes, int n_in,
                              void* d_out, int out_size, void* d_ws, size_t ws_size,
                              hipStream_t stream) {
  const float* space  = (const float*)d_in[0];
  const float* timec  = (const float*)d_in[1];
  const float* stData = (const float*)d_in[2];
  const float* tspace = (const float*)d_in[3];
  const float* ttime  = (const float*)d_in[4];
  const float* l_ll   = (const float*)d_in[5];
  const float* l_el   = (const float*)d_in[6];
  const float* l_t    = (const float*)d_in[7];
  const float* l_nv   = (const float*)d_in[8];
  const float* l_sv   = (const float*)d_in[9];
  const float* bias   = (const float*)d_in[10];
  const float* gain   = (const float*)d_in[11];
  float* ws  = (float*)d_ws;
  float* out = (float*)d_out;

  // Jacobi LDS: 2 * 100*101 floats + 4 * 50 (c,s,p,q) = 81600 bytes (>64K needs opt-in)
  const int JAC_LDS = 2 * 100 * 101 * 4 + 4 * 50 * 4;
  hipFuncSetAttribute((const void*)jacobi_kernel,
                      hipFuncAttributeMaxDynamicSharedMemorySize, JAC_LDS);

  build_kernel<<<(BUILD_TOTAL + 255) / 256, 256, 0, stream>>>(
      space, timec, stData, tspace, ttime, l_ll, l_el, l_t, bias, gain, ws);

  jacobi_kernel<<<2, 256, JAC_LDS, stream>>>(
      ws + OFF_S, ws + OFF_EWS, ws + OFF_VS,
      ws + OFF_T, ws + OFF_EWT, ws + OFF_VT);

  auto grid = [](int mn) { return dim3((mn + 255) / 256); };

  // P1 = VS^T @ Y                               [64,100]
  gemm_k<<<grid(6400), 256, 0, stream>>>(ws + OFF_VS, ws + OFF_Y, ws + OFF_P1,
      64, 100, 64, 1, 0, 0, nullptr, nullptr, nullptr);
  // tilde = (P1 @ VT) / (wS wT^T + sigma^2)     [64,100]
  gemm_k<<<grid(6400), 256, 0, stream>>>(ws + OFF_P1, ws + OFF_VT, ws + OFF_TILDE,
      64, 100, 100, 0, 0, 1, ws + OFF_EWS, ws + OFF_EWT, l_nv);
  // P3 = VS @ tilde                             [64,100]
  gemm_k<<<grid(6400), 256, 0, stream>>>(ws + OFF_VS, ws + OFF_TILDE, ws + OFF_P3,
      64, 100, 64, 0, 0, 0, nullptr, nullptr, nullptr);
  // Alpha = P3 @ VT^T                           [64,100]
  gemm_k<<<grid(6400), 256, 0, stream>>>(ws + OFF_P3, ws + OFF_VT, ws + OFF_ALPHA,
      64, 100, 100, 0, 1, 0, nullptr, nullptr, nullptr);
  // P4 = Ks @ Alpha                             [64,100]
  gemm_k<<<grid(6400), 256, 0, stream>>>(ws + OFF_KS, ws + OFF_ALPHA, ws + OFF_P4,
      64, 100, 64, 0, 0, 0, nullptr, nullptr, nullptr);
  // yPred = P4 @ Kt^T  -> out[0:6400]           [64,100]
  gemm_k<<<grid(6400), 256, 0, stream>>>(ws + OFF_P4, ws + OFF_KT, out,
      64, 100, 100, 0, 1, 0, nullptr, nullptr, nullptr);
  // U2 = (Kt @ VT)^2                            [100,100]
  gemm_k<<<grid(10000), 256, 0, stream>>>(ws + OFF_KT, ws + OFF_VT, ws + OFF_U2,
      100, 100, 100, 0, 0, 2, nullptr, nullptr, nullptr);
  // W2 = (Ks @ VS)^2                            [64,64]
  gemm_k<<<grid(4096), 256, 0, stream>>>(ws + OFF_KS, ws + OFF_VS, ws + OFF_W2,
      64, 64, 64, 0, 0, 2, nullptr, nullptr, nullptr);
  // Z = R @ U2^T, R[q][p] = 1/(wS[q]wT[p]+s2)   [64,100]
  gemm_k<<<grid(6400), 256, 0, stream>>>(nullptr, ws + OFF_U2, ws + OFF_Z,
      64, 100, 100, 2, 1, 0, ws + OFF_EWS, ws + OFF_EWT, l_nv);
  // yVar = exp(lsv) - W2 @ Z  -> out[6400:]     [64,100]
  gemm_k<<<grid(6400), 256, 0, stream>>>(ws + OFF_W2, ws + OFF_Z, out + 6400,
      64, 100, 64, 0, 0, 3, nullptr, nullptr, l_sv);
}

// Round 3
// 2051.308 us; speedup vs baseline: 3.4506x; 3.4506x over previous
//
#include <hip/hip_runtime.h>
#include <math.h>

#define JITTER 0.001f

// ---- workspace layout (float offsets) ----
enum {
  OFF_S     = 0,            // 64x64 spatial kernel
  OFF_T     = 4096,         // 100x100 temporal kernel
  OFF_KS    = 14096,        // 64x64 test-spatial  [Ms,Ns]
  OFF_KT    = 18192,        // 100x100 test-temporal [Mt,Nt]
  OFF_Y     = 28192,        // 64x100 calibrated data
  OFF_EWS   = 34592,        // 64  spatial eigenvalues
  OFF_VS    = 34656,        // 64x64 spatial eigenvectors (columns)
  OFF_EWT   = 38752,        // 100 temporal eigenvalues
  OFF_VT    = 38852,        // 100x100 temporal eigenvectors (columns)
  OFF_P1    = 48852,        // 64x100 temp
  OFF_TILDE = 55252,        // 64x100 temp
  OFF_P3    = 61652,        // 64x100 temp
  OFF_ALPHA = 68052,        // 64x100 Alpha matrix
  OFF_P4    = 74452,        // 64x100 temp
  OFF_U2    = 80852,        // 100x100 (Kt@VT)^2
  OFF_W2    = 90852,        // 64x64  (Ks@VS)^2
  OFF_Z     = 94948,        // 64x100 R @ U2^T
  WS_FLOATS = 101348
};

#define BUILD_TOTAL (4096 + 10000 + 4096 + 10000 + 6400)

__global__ void __launch_bounds__(256) build_kernel(
    const float* __restrict__ space, const float* __restrict__ timec,
    const float* __restrict__ stData, const float* __restrict__ tspace,
    const float* __restrict__ ttime, const float* __restrict__ l_ll,
    const float* __restrict__ l_el, const float* __restrict__ l_t,
    const float* __restrict__ bias, const float* __restrict__ gain,
    float* __restrict__ ws)
{
  int idx = blockIdx.x * blockDim.x + threadIdx.x;
  if (idx >= BUILD_TOTAL) return;
  float inv_ll = expf(-l_ll[0]);
  float inv_el = expf(-l_el[0]);
  float inv_t  = expf(-l_t[0]);

  if (idx < 4096) {
    int i = idx >> 6, j = idx & 63;
    float dx0 = (space[i*3+0] - space[j*3+0]) * inv_ll;
    float dx1 = (space[i*3+1] - space[j*3+1]) * inv_ll;
    float dz  = (space[i*3+2] - space[j*3+2]) * inv_el;
    float v = expf(-(dx0*dx0 + dx1*dx1)) * expf(-(dz*dz));
    if (i == j) v += JITTER;
    ws[OFF_S + idx] = v;
  } else if (idx < 14096) {
    int k = idx - 4096;
    int t = k / 100, u = k % 100;
    float d = (timec[t] - timec[u]) * inv_t;
    float v = expf(-d*d);
    if (t == u) v += JITTER;
    ws[OFF_T + k] = v;
  } else if (idx < 18192) {
    int k = idx - 14096;
    int i = k >> 6, j = k & 63;
    float dx0 = (tspace[i*3+0] - space[j*3+0]) * inv_ll;
    float dx1 = (tspace[i*3+1] - space[j*3+1]) * inv_ll;
    float dz  = (tspace[i*3+2] - space[j*3+2]) * inv_el;
    ws[OFF_KS + k] = expf(-(dx0*dx0 + dx1*dx1)) * expf(-(dz*dz));
  } else if (idx < 28192) {
    int k = idx - 18192;
    int j = k / 100, t = k % 100;
    float d = (ttime[j] - timec[t]) * inv_t;
    ws[OFF_KT + k] = expf(-d*d);
  } else {
    int k = idx - 28192;
    int s = k / 100;
    ws[OFF_Y + k] = stData[k] * gain[0] + bias[s];
  }
}

// ---- parallel-ordering two-sided Jacobi, compile-time N, 1024 threads ----
template<int N, int SWEEPS>
__device__ __forceinline__ void jacobi_body(
    const float* __restrict__ Ain, float* __restrict__ wout,
    float* __restrict__ Vout, float* lds)
{
  constexpr int STRIDE = N + 1;       // odd -> conflict-free column access
  constexpr int NP = N / 2;
  constexpr int NTH = 1024;
  constexpr int ITER = (NP * N + NTH - 1) / NTH;
  float* A = lds;
  float* V = A + N * STRIDE;
  float4* par = (float4*)(V + N * STRIDE);   // 16B-aligned (checked offsets)
  const int tid = threadIdx.x;

  for (int idx = tid; idx < N * N; idx += NTH) {
    int i = idx / N, j = idx - i * N;
    A[i * STRIDE + j] = Ain[idx];
    V[i * STRIDE + j] = (i == j) ? 1.0f : 0.0f;
  }
  __syncthreads();

  for (int sw = 0; sw < SWEEPS; ++sw) {
    for (int r = 0; r < N - 1; ++r) {
      // 1) rotation params per pair (round-robin tournament), packed float4
      if (tid < NP) {
        int p, q;
        if (tid == 0) { p = N - 1; q = r; }
        else {
          p = (r + tid) % (N - 1);
          q = (r - tid + (N - 1)) % (N - 1);
        }
        if (p > q) { int t = p; p = q; q = t; }
        float apq = A[p * STRIDE + q];
        float app = A[p * STRIDE + p];
        float aqq = A[q * STRIDE + q];
        float c, s;
        if (fabsf(apq) < 1e-36f) { c = 1.0f; s = 0.0f; }
        else {
          float theta = (aqq - app) / (2.0f * apq);
          float tt = 1.0f / (fabsf(theta) + sqrtf(1.0f + theta * theta));
          if (theta < 0.0f) tt = -tt;
          c = 1.0f / sqrtf(1.0f + tt * tt);
          s = tt * c;
        }
        par[tid] = make_float4(c, s, __int_as_float(p), __int_as_float(q));
      }
      __syncthreads();
      // 2) row update: A <- J^T A   (contiguous in j, coalesced banks)
      #pragma unroll
      for (int t = 0; t < ITER; ++t) {
        int w = tid + t * NTH;
        if (w < NP * N) {
          int k = w / N, j = w - k * N;         // compile-time N -> magic mul
          float4 P = par[k];                    // one ds_read_b128, broadcast
          int p = __float_as_int(P.z), q = __float_as_int(P.w);
          float ap = A[p * STRIDE + j], aq = A[q * STRIDE + j];
          A[p * STRIDE + j] = P.x * ap - P.y * aq;
          A[q * STRIDE + j] = P.y * ap + P.x * aq;
        }
      }
      __syncthreads();
      // 3) column update: A <- A J,  V <- V J  (stride odd -> no conflicts)
      #pragma unroll
      for (int t = 0; t < ITER; ++t) {
        int w = tid + t * NTH;
        if (w < NP * N) {
          int k = w / N, i = w - k * N;
          float4 P = par[k];
          int p = __float_as_int(P.z), q = __float_as_int(P.w);
          float aip = A[i * STRIDE + p], aiq = A[i * STRIDE + q];
          A[i * STRIDE + p] = P.x * aip - P.y * aiq;
          A[i * STRIDE + q] = P.y * aip + P.x * aiq;
          float vip = V[i * STRIDE + p], viq = V[i * STRIDE + q];
          V[i * STRIDE + p] = P.x * vip - P.y * viq;
          V[i * STRIDE + q] = P.y * vip + P.x * viq;
        }
      }
      __syncthreads();
    }
  }

  for (int idx = tid; idx < N * N; idx += NTH) {
    int i = idx / N, j = idx - i * N;
    Vout[idx] = V[i * STRIDE + j];
  }
  for (int i = tid; i < N; i += NTH) wout[i] = A[i * STRIDE + i];
}

__global__ void __launch_bounds__(1024) jacobi_kernel(
    const float* __restrict__ Sin, float* __restrict__ wS, float* __restrict__ VSo,
    const float* __restrict__ Tin, float* __restrict__ wT, float* __restrict__ VTo)
{
  extern __shared__ float lds[];
  if (blockIdx.x == 0) jacobi_body<64, 7>(Sin, wS, VSo, lds);
  else                 jacobi_body<100, 8>(Tin, wT, VTo, lds);
}

// ---- generic tiny GEMM: one thread per output element ----
// tA: 0 = A[m][k], 1 = A[k][m], 2 = a = 1/(w1[m]*w2[k] + exp(*scal))
// tB: 0 = B[k][n], 1 = B[n][k]
// mode: 0 = acc, 1 = acc/(w1[m]*w2[n]+exp(*scal)), 2 = acc^2, 3 = exp(*scal)-acc
__global__ void __launch_bounds__(256) gemm_k(
    const float* __restrict__ A, const float* __restrict__ B,
    float* __restrict__ C, int M, int N, int K, int tA, int tB, int mode,
    const float* __restrict__ w1, const float* __restrict__ w2,
    const float* __restrict__ scal)
{
  int idx = blockIdx.x * blockDim.x + threadIdx.x;
  if (idx >= M * N) return;
  int m = idx / N, n = idx - m * N;
  float nv = (scal != nullptr) ? expf(scal[0]) : 0.0f;
  float acc = 0.0f;
  for (int k = 0; k < K; ++k) {
    float a;
    if (tA == 2)      a = 1.0f / (w1[m] * w2[k] + nv);
    else if (tA == 1) a = A[k * M + m];
    else              a = A[m * K + k];
    float b = tB ? B[n * K + k] : B[k * N + n];
    acc += a * b;
  }
  float out;
  if (mode == 1)      out = acc / (w1[m] * w2[n] + nv);
  else if (mode == 2) out = acc * acc;
  else if (mode == 3) out = nv - acc;
  else                out = acc;
  C[idx] = out;
}

extern "C" void kernel_launch(void* const* d_in, const int* in_sizes, int n_in,
                              void* d_out, int out_size, void* d_ws, size_t ws_size,
                              hipStream_t stream) {
  const float* space  = (const float*)d_in[0];
  const float* timec  = (const float*)d_in[1];
  const float* stData = (const float*)d_in[2];
  const float* tspace = (const float*)d_in[3];
  const float* ttime  = (const float*)d_in[4];
  const float* l_ll   = (const float*)d_in[5];
  const float* l_el   = (const float*)d_in[6];
  const float* l_t    = (const float*)d_in[7];
  const float* l_nv   = (const float*)d_in[8];
  const float* l_sv   = (const float*)d_in[9];
  const float* bias   = (const float*)d_in[10];
  const float* gain   = (const float*)d_in[11];
  float* ws  = (float*)d_ws;
  float* out = (float*)d_out;

  // Jacobi LDS: 2 * 100*101 floats + 50 float4 = 81600 bytes (>64K opt-in)
  const int JAC_LDS = 2 * 100 * 101 * 4 + 50 * 16;
  hipFuncSetAttribute((const void*)jacobi_kernel,
                      hipFuncAttributeMaxDynamicSharedMemorySize, JAC_LDS);

  build_kernel<<<(BUILD_TOTAL + 255) / 256, 256, 0, stream>>>(
      space, timec, stData, tspace, ttime, l_ll, l_el, l_t, bias, gain, ws);

  jacobi_kernel<<<2, 1024, JAC_LDS, stream>>>(
      ws + OFF_S, ws + OFF_EWS, ws + OFF_VS,
      ws + OFF_T, ws + OFF_EWT, ws + OFF_VT);

  auto grid = [](int mn) { return dim3((mn + 255) / 256); };

  // P1 = VS^T @ Y                               [64,100]
  gemm_k<<<grid(6400), 256, 0, stream>>>(ws + OFF_VS, ws + OFF_Y, ws + OFF_P1,
      64, 100, 64, 1, 0, 0, nullptr, nullptr, nullptr);
  // tilde = (P1 @ VT) / (wS wT^T + sigma^2)     [64,100]
  gemm_k<<<grid(6400), 256, 0, stream>>>(ws + OFF_P1, ws + OFF_VT, ws + OFF_TILDE,
      64, 100, 100, 0, 0, 1, ws + OFF_EWS, ws + OFF_EWT, l_nv);
  // P3 = VS @ tilde                             [64,100]
  gemm_k<<<grid(6400), 256, 0, stream>>>(ws + OFF_VS, ws + OFF_TILDE, ws + OFF_P3,
      64, 100, 64, 0, 0, 0, nullptr, nullptr, nullptr);
  // Alpha = P3 @ VT^T                           [64,100]
  gemm_k<<<grid(6400), 256, 0, stream>>>(ws + OFF_P3, ws + OFF_VT, ws + OFF_ALPHA,
      64, 100, 100, 0, 1, 0, nullptr, nullptr, nullptr);
  // P4 = Ks @ Alpha                             [64,100]
  gemm_k<<<grid(6400), 256, 0, stream>>>(ws + OFF_KS, ws + OFF_ALPHA, ws + OFF_P4,
      64, 100, 64, 0, 0, 0, nullptr, nullptr, nullptr);
  // yPred = P4 @ Kt^T  -> out[0:6400]           [64,100]
  gemm_k<<<grid(6400), 256, 0, stream>>>(ws + OFF_P4, ws + OFF_KT, out,
      64, 100, 100, 0, 1, 0, nullptr, nullptr, nullptr);
  // U2 = (Kt @ VT)^2                            [100,100]
  gemm_k<<<grid(10000), 256, 0, stream>>>(ws + OFF_KT, ws + OFF_VT, ws + OFF_U2,
      100, 100, 100, 0, 0, 2, nullptr, nullptr, nullptr);
  // W2 = (Ks @ VS)^2                            [64,64]
  gemm_k<<<grid(4096), 256, 0, stream>>>(ws + OFF_KS, ws + OFF_VS, ws + OFF_W2,
      64, 64, 64, 0, 0, 2, nullptr, nullptr, nullptr);
  // Z = R @ U2^T, R[q][p] = 1/(wS[q]wT[p]+s2)   [64,100]
  gemm_k<<<grid(6400), 256, 0, stream>>>(nullptr, ws + OFF_U2, ws + OFF_Z,
      64, 100, 100, 2, 1, 0, ws + OFF_EWS, ws + OFF_EWT, l_nv);
  // yVar = exp(lsv) - W2 @ Z  -> out[6400:]     [64,100]
  gemm_k<<<grid(6400), 256, 0, stream>>>(ws + OFF_W2, ws + OFF_Z, out + 6400,
      64, 100, 64, 0, 0, 3, nullptr, nullptr, l_sv);
}

// Round 4
// 1876.104 us; speedup vs baseline: 3.7728x; 1.0934x over previous
//
#include <hip/hip_runtime.h>
#include <math.h>

#define JITTER 0.001f

// ---- workspace layout (float offsets) ----
enum {
  OFF_KS    = 0,        // 64x64   test-spatial [Ms,Ns]
  OFF_KT    = 4096,     // 100x100 test-temporal [Mt,Nt]
  OFF_Y     = 14096,    // 64x100  calibrated data
  OFF_EWS   = 20496,    // 64      spatial eigenvalues
  OFF_VS    = 20560,    // 64x64   VS^T (row e = eigenvector e)
  OFF_EWT   = 24656,    // 100     temporal eigenvalues
  OFF_VT    = 24756,    // 100x100 VT^T
  OFF_P1    = 34756,    // 64x100
  OFF_TILDE = 41156,    // 64x100
  OFF_M1    = 47556,    // 64x100
  OFF_GS    = 53956,    // 64x64   Ks@VS
  OFF_GT    = 58052,    // 100x100 Kt@VT
  OFF_U2    = 68052,    // 100x100 GT^2
  OFF_W2    = 78052,    // 64x64   GS^2
  OFF_Z     = 82148,    // 64x100
  WS_FLOATS = 88548
};

#define BUILD2_TOTAL (4096 + 10000 + 6400)

// Ks, Kt, Y only (S and T are built inside the jacobi kernel)
__global__ void __launch_bounds__(256) build2_kernel(
    const float* __restrict__ space, const float* __restrict__ timec,
    const float* __restrict__ stData, const float* __restrict__ tspace,
    const float* __restrict__ ttime, const float* __restrict__ l_ll,
    const float* __restrict__ l_el, const float* __restrict__ l_t,
    const float* __restrict__ bias, const float* __restrict__ gain,
    float* __restrict__ ws)
{
  int idx = blockIdx.x * blockDim.x + threadIdx.x;
  if (idx >= BUILD2_TOTAL) return;
  float inv_ll = expf(-l_ll[0]);
  float inv_el = expf(-l_el[0]);
  float inv_t  = expf(-l_t[0]);
  if (idx < 4096) {
    int i = idx >> 6, j = idx & 63;
    float dx0 = (tspace[i*3+0] - space[j*3+0]) * inv_ll;
    float dx1 = (tspace[i*3+1] - space[j*3+1]) * inv_ll;
    float dz  = (tspace[i*3+2] - space[j*3+2]) * inv_el;
    ws[OFF_KS + idx] = expf(-(dx0*dx0 + dx1*dx1)) * expf(-(dz*dz));
  } else if (idx < 14096) {
    int k = idx - 4096;
    int j = k / 100, t = k % 100;
    float d = (ttime[j] - timec[t]) * inv_t;
    ws[OFF_KT + k] = expf(-d*d);
  } else {
    int k = idx - 14096;
    int s = k / 100;
    ws[OFF_Y + k] = stData[k] * gain[0] + bias[s];
  }
}

// ---- parallel two-sided Jacobi; A scalar (odd stride), W=V^T float4 rows ----
template<int N, int SWEEPS, int SPATIAL>
__device__ __forceinline__ void jacobi_body(
    const float* __restrict__ c0, const float* __restrict__ c1, float ia, float ib,
    float* __restrict__ wout, float* __restrict__ Vout, float* lds)
{
  constexpr int SA  = N + 1;              // odd -> conflict-free rows AND cols
  constexpr int SW  = (N + 7) & ~3;       // mult of 4 -> float4 rows (104 / 68)
  constexpr int NP  = N / 2;
  constexpr int NTH = 1024;
  constexpr int NC  = N / 4;              // float4 chunks per W row
  constexpr int IA  = (NP * N  + NTH - 1) / NTH;   // A row/col items per thread
  constexpr int IW  = (NP * NC + NTH - 1) / NTH;   // W row items per thread
  float*  A   = lds;
  float*  W   = A + N * SA;
  float4* par = (float4*)(W + N * SW);    // offsets are 16B-aligned
  const int tid = threadIdx.x;

  // build A in LDS directly; W = I
  for (int idx = tid; idx < N * N; idx += NTH) {
    int i = idx / N, j = idx - i * N;
    float v;
    if (SPATIAL) {
      float dx0 = (c0[i*3+0] - c0[j*3+0]) * ia;
      float dx1 = (c0[i*3+1] - c0[j*3+1]) * ia;
      float dz  = (c0[i*3+2] - c0[j*3+2]) * ib;
      v = expf(-(dx0*dx0 + dx1*dx1)) * expf(-(dz*dz));
    } else {
      float d = (c1[i] - c1[j]) * ia;
      v = expf(-d*d);
    }
    if (i == j) v += JITTER;
    A[i * SA + j] = v;
    W[i * SW + j] = (i == j) ? 1.0f : 0.0f;
  }
  __syncthreads();

  for (int sw = 0; sw < SWEEPS; ++sw) {
    for (int r = 0; r < N - 1; ++r) {
      // phase 1: rotation params (round-robin tournament), 1 wave
      if (tid < NP) {
        int p, q;
        if (tid == 0) { p = N - 1; q = r; }
        else {
          p = r + tid;        if (p >= N - 1) p -= N - 1;
          q = r - tid;        if (q < 0)      q += N - 1;
        }
        if (p > q) { int t = p; p = q; q = t; }
        float apq = A[p * SA + q];
        float app = A[p * SA + p];
        float aqq = A[q * SA + q];
        float c, s;
        if (fabsf(apq) < 1e-36f) { c = 1.0f; s = 0.0f; }
        else {
          float theta = (aqq - app) / (2.0f * apq);
          float tt = 1.0f / (fabsf(theta) + sqrtf(1.0f + theta * theta));
          if (theta < 0.0f) tt = -tt;
          c = 1.0f / sqrtf(1.0f + tt * tt);
          s = tt * c;
        }
        par[tid] = make_float4(c, s, __int_as_float(p), __int_as_float(q));
      }
      __syncthreads();

      // phase 2: row updates  A <- J^T A  (scalar) and  W <- J^T W  (float4)
      // preload ALL reads, then write (items are disjoint -> safe)
      {
        float a0[IA], a1[IA]; float cx[IA], cy[IA]; int d0[IA], d1[IA];
        float4 w0[IW], w1[IW]; float ux[IW], uy[IW]; int e0[IW], e1[IW];
        #pragma unroll
        for (int t = 0; t < IA; ++t) {
          int w = tid + t * NTH;
          if (w < NP * N) {
            int k = w / N, j = w - k * N;
            float4 P = par[k];
            int p = __float_as_int(P.z), q = __float_as_int(P.w);
            d0[t] = p * SA + j; d1[t] = q * SA + j;
            a0[t] = A[d0[t]];   a1[t] = A[d1[t]];
            cx[t] = P.x;        cy[t] = P.y;
          }
        }
        #pragma unroll
        for (int t = 0; t < IW; ++t) {
          int w = tid + t * NTH;
          if (w < NP * NC) {
            int k = w / NC, c = w - k * NC;
            float4 P = par[k];
            int p = __float_as_int(P.z), q = __float_as_int(P.w);
            e0[t] = p * (SW/4) + c; e1[t] = q * (SW/4) + c;
            w0[t] = ((float4*)W)[e0[t]]; w1[t] = ((float4*)W)[e1[t]];
            ux[t] = P.x; uy[t] = P.y;
          }
        }
        #pragma unroll
        for (int t = 0; t < IA; ++t) {
          int w = tid + t * NTH;
          if (w < NP * N) {
            A[d0[t]] = cx[t] * a0[t] - cy[t] * a1[t];
            A[d1[t]] = cy[t] * a0[t] + cx[t] * a1[t];
          }
        }
        #pragma unroll
        for (int t = 0; t < IW; ++t) {
          int w = tid + t * NTH;
          if (w < NP * NC) {
            float c = ux[t], s = uy[t];
            float4 r0, r1;
            r0.x = c*w0[t].x - s*w1[t].x;  r1.x = s*w0[t].x + c*w1[t].x;
            r0.y = c*w0[t].y - s*w1[t].y;  r1.y = s*w0[t].y + c*w1[t].y;
            r0.z = c*w0[t].z - s*w1[t].z;  r1.z = s*w0[t].z + c*w1[t].z;
            r0.w = c*w0[t].w - s*w1[t].w;  r1.w = s*w0[t].w + c*w1[t].w;
            ((float4*)W)[e0[t]] = r0; ((float4*)W)[e1[t]] = r1;
          }
        }
      }
      __syncthreads();

      // phase 3: column update  A <- A J  (scalar, odd stride -> conflict-free)
      {
        float a0[IA], a1[IA]; float cx[IA], cy[IA]; int d0[IA], d1[IA];
        #pragma unroll
        for (int t = 0; t < IA; ++t) {
          int w = tid + t * NTH;
          if (w < NP * N) {
            int k = w / N, i = w - k * N;
            float4 P = par[k];
            int p = __float_as_int(P.z), q = __float_as_int(P.w);
            d0[t] = i * SA + p; d1[t] = i * SA + q;
            a0[t] = A[d0[t]];   a1[t] = A[d1[t]];
            cx[t] = P.x;        cy[t] = P.y;
          }
        }
        #pragma unroll
        for (int t = 0; t < IA; ++t) {
          int w = tid + t * NTH;
          if (w < NP * N) {
            A[d0[t]] = cx[t] * a0[t] - cy[t] * a1[t];
            A[d1[t]] = cy[t] * a0[t] + cx[t] * a1[t];
          }
        }
      }
      __syncthreads();
    }
  }

  // output W = V^T (row-major), eigenvalues = diag(A)
  for (int idx = tid; idx < N * N; idx += NTH) {
    int i = idx / N, j = idx - i * N;
    Vout[idx] = W[i * SW + j];
  }
  for (int i = tid; i < N; i += NTH) wout[i] = A[i * SA + i];
}

__global__ void __launch_bounds__(1024) jacobi_kernel(
    const float* __restrict__ space, const float* __restrict__ timec,
    const float* __restrict__ l_ll, const float* __restrict__ l_el,
    const float* __restrict__ l_t,
    float* __restrict__ wS, float* __restrict__ VSo,
    float* __restrict__ wT, float* __restrict__ VTo)
{
  extern __shared__ float lds[];
  if (blockIdx.x == 0)
    jacobi_body<64, 7, 1>(space, nullptr, expf(-l_ll[0]), expf(-l_el[0]), wS, VSo, lds);
  else
    jacobi_body<100, 8, 0>(nullptr, timec, expf(-l_t[0]), 0.0f, wT, VTo, lds);
}

// ---- generic tiny GEMM: one thread per output ----
// tA: 0=A[m][k], 1=A[k][m], 2=a=1/(w1[m]*w2[k]+exp(*scal))
// tB: 0=B[k][n], 1=B[n][k]
// mode: 0=acc, 1=acc/(w1[m]*w2[n]+exp(*scal)), 3=exp(*scal)-acc,
//       4=write C=acc and C2=acc^2
__global__ void __launch_bounds__(256) gemm_k(
    const float* __restrict__ A, const float* __restrict__ B,
    float* __restrict__ C, float* __restrict__ C2,
    int M, int N, int K, int tA, int tB, int mode,
    const float* __restrict__ w1, const float* __restrict__ w2,
    const float* __restrict__ scal)
{
  int idx = blockIdx.x * blockDim.x + threadIdx.x;
  if (idx >= M * N) return;
  int m = idx / N, n = idx - m * N;
  float nv = (scal != nullptr) ? expf(scal[0]) : 0.0f;
  float acc = 0.0f;
  for (int k = 0; k < K; ++k) {
    float a;
    if (tA == 2)      a = 1.0f / (w1[m] * w2[k] + nv);
    else if (tA == 1) a = A[k * M + m];
    else              a = A[m * K + k];
    float b = tB ? B[n * K + k] : B[k * N + n];
    acc += a * b;
  }
  if (mode == 4) { C[idx] = acc; C2[idx] = acc * acc; return; }
  float out;
  if (mode == 1)      out = acc / (w1[m] * w2[n] + nv);
  else if (mode == 3) out = nv - acc;
  else                out = acc;
  C[idx] = out;
}

extern "C" void kernel_launch(void* const* d_in, const int* in_sizes, int n_in,
                              void* d_out, int out_size, void* d_ws, size_t ws_size,
                              hipStream_t stream) {
  const float* space  = (const float*)d_in[0];
  const float* timec  = (const float*)d_in[1];
  const float* stData = (const float*)d_in[2];
  const float* tspace = (const float*)d_in[3];
  const float* ttime  = (const float*)d_in[4];
  const float* l_ll   = (const float*)d_in[5];
  const float* l_el   = (const float*)d_in[6];
  const float* l_t    = (const float*)d_in[7];
  const float* l_nv   = (const float*)d_in[8];
  const float* l_sv   = (const float*)d_in[9];
  const float* bias   = (const float*)d_in[10];
  const float* gain   = (const float*)d_in[11];
  float* ws  = (float*)d_ws;
  float* out = (float*)d_out;

  // LDS for n=100 block: A 100*101 + W 100*104 + par 50*4 floats = 82800 B
  const int JAC_LDS = (100*101 + 100*104 + 50*4) * 4;
  hipFuncSetAttribute((const void*)jacobi_kernel,
                      hipFuncAttributeMaxDynamicSharedMemorySize, JAC_LDS);

  build2_kernel<<<(BUILD2_TOTAL + 255) / 256, 256, 0, stream>>>(
      space, timec, stData, tspace, ttime, l_ll, l_el, l_t, bias, gain, ws);

  jacobi_kernel<<<2, 1024, JAC_LDS, stream>>>(
      space, timec, l_ll, l_el, l_t,
      ws + OFF_EWS, ws + OFF_VS, ws + OFF_EWT, ws + OFF_VT);

  auto grid = [](int mn) { return dim3((mn + 255) / 256); };
  float* NUL = nullptr;

  // GS = Ks @ VS (VS^T stored -> tB=1), also W2 = GS^2      [64,64,64]
  gemm_k<<<grid(4096), 256, 0, stream>>>(ws + OFF_KS, ws + OFF_VS,
      ws + OFF_GS, ws + OFF_W2, 64, 64, 64, 0, 1, 4, NUL, NUL, NUL);
  // GT = Kt @ VT (VT^T stored -> tB=1), also U2 = GT^2      [100,100,100]
  gemm_k<<<grid(10000), 256, 0, stream>>>(ws + OFF_KT, ws + OFF_VT,
      ws + OFF_GT, ws + OFF_U2, 100, 100, 100, 0, 1, 4, NUL, NUL, NUL);
  // P1 = VS^T @ Y (stored row-major -> tA=0)                [64,100,64]
  gemm_k<<<grid(6400), 256, 0, stream>>>(ws + OFF_VS, ws + OFF_Y,
      ws + OFF_P1, NUL, 64, 100, 64, 0, 0, 0, NUL, NUL, NUL);
  // tilde = (P1 @ VT) / (wS wT^T + s2)  (VT^T -> tB=1)      [64,100,100]
  gemm_k<<<grid(6400), 256, 0, stream>>>(ws + OFF_P1, ws + OFF_VT,
      ws + OFF_TILDE, NUL, 64, 100, 100, 0, 1, 1, ws + OFF_EWS, ws + OFF_EWT, l_nv);
  // Z = R @ U2^T, R[q][p]=1/(wS[q]wT[p]+s2)                 [64,100,100]
  gemm_k<<<grid(6400), 256, 0, stream>>>(NUL, ws + OFF_U2,
      ws + OFF_Z, NUL, 64, 100, 100, 2, 1, 0, ws + OFF_EWS, ws + OFF_EWT, l_nv);
  // M1 = GS @ tilde                                         [64,100,64]
  gemm_k<<<grid(6400), 256, 0, stream>>>(ws + OFF_GS, ws + OFF_TILDE,
      ws + OFF_M1, NUL, 64, 100, 64, 0, 0, 0, NUL, NUL, NUL);
  // yPred = M1 @ GT^T -> out[0:6400]                        [64,100,100]
  gemm_k<<<grid(6400), 256, 0, stream>>>(ws + OFF_M1, ws + OFF_GT,
      out, NUL, 64, 100, 100, 0, 1, 0, NUL, NUL, NUL);
  // yVar = exp(lsv) - W2 @ Z -> out[6400:]                  [64,100,64]
  gemm_k<<<grid(6400), 256, 0, stream>>>(ws + OFF_W2, ws + OFF_Z,
      out + 6400, NUL, 64, 100, 64, 0, 0, 3, NUL, NUL, l_sv);
}

// Round 5
// 1105.640 us; speedup vs baseline: 6.4019x; 1.6968x over previous
//
#include <hip/hip_runtime.h>
#include <math.h>

#define JITTER 0.001f

// ---- workspace layout (float offsets) ----
enum {
  OFF_KS    = 0,        // 64x64   test-spatial [Ms,Ns]
  OFF_KT    = 4096,     // 100x100 test-temporal [Mt,Nt]
  OFF_Y     = 14096,    // 64x100  calibrated data
  OFF_EWS   = 20496,    // 64      spatial eigenvalues
  OFF_VS    = 20560,    // 64x64   VS^T (row e = eigenvector e)
  OFF_EWT   = 24656,    // 100     temporal eigenvalues
  OFF_VT    = 24756,    // 100x100 VT^T
  OFF_P1    = 34756,    // 64x100
  OFF_TILDE = 41156,    // 64x100
  OFF_M1    = 47556,    // 64x100
  OFF_GS    = 53956,    // 64x64   Ks@VS
  OFF_GT    = 58052,    // 100x100 Kt@VT
  OFF_U2    = 68052,    // 100x100 GT^2
  OFF_W2    = 78052,    // 64x64   GS^2
  OFF_Z     = 82148,    // 64x100
  WS_FLOATS = 88548
};

#define BUILD2_TOTAL (4096 + 10000 + 6400)

// Ks, Kt, Y only (S and T are built inside the jacobi kernel)
__global__ void __launch_bounds__(256) build2_kernel(
    const float* __restrict__ space, const float* __restrict__ timec,
    const float* __restrict__ stData, const float* __restrict__ tspace,
    const float* __restrict__ ttime, const float* __restrict__ l_ll,
    const float* __restrict__ l_el, const float* __restrict__ l_t,
    const float* __restrict__ bias, const float* __restrict__ gain,
    float* __restrict__ ws)
{
  int idx = blockIdx.x * blockDim.x + threadIdx.x;
  if (idx >= BUILD2_TOTAL) return;
  float inv_ll = expf(-l_ll[0]);
  float inv_el = expf(-l_el[0]);
  float inv_t  = expf(-l_t[0]);
  if (idx < 4096) {
    int i = idx >> 6, j = idx & 63;
    float dx0 = (tspace[i*3+0] - space[j*3+0]) * inv_ll;
    float dx1 = (tspace[i*3+1] - space[j*3+1]) * inv_ll;
    float dz  = (tspace[i*3+2] - space[j*3+2]) * inv_el;
    ws[OFF_KS + idx] = expf(-(dx0*dx0 + dx1*dx1)) * expf(-(dz*dz));
  } else if (idx < 14096) {
    int k = idx - 4096;
    int j = k / 100, t = k % 100;
    float d = (ttime[j] - timec[t]) * inv_t;
    ws[OFF_KT + k] = expf(-d*d);
  } else {
    int k = idx - 14096;
    int s = k / 100;
    ws[OFF_Y + k] = stData[k] * gain[0] + bias[s];
  }
}

// ---- parallel two-sided Jacobi, fused symmetric 2x2-block update ----
// A kept full+symmetric (odd stride); W = V^T float4 rows.
// Per round: phase1 = rotation params (1 wave); phase2 = all (k1<=k2) 2x2
// blocks M <- J_k1^T M J_k2 (mirror-write lower copy) + W row rotations.
template<int N, int SWEEPS, int SPATIAL>
__device__ __forceinline__ void jacobi_body(
    const float* __restrict__ c0, const float* __restrict__ c1, float ia, float ib,
    float* __restrict__ wout, float* __restrict__ Vout, float* lds)
{
  constexpr int SA  = N + 1;              // odd -> conflict-free rows AND cols
  constexpr int SW  = (N + 7) & ~3;       // 104 / 68: float4 rows
  constexpr int NP  = N / 2;              // pairs per round
  constexpr int NTH = 1024;
  constexpr int NC  = SW / 4;             // float4 chunks per W row (26 / 17)
  constexpr int NB  = NP * (NP + 1) / 2;  // 2x2 blocks (1275 / 528)
  constexpr int NWI = NP * NC;            // W items (1300 / 544)
  float*  A   = lds;
  float*  W   = A + N * SA;
  float4* par = (float4*)(W + N * SW);
  const int tid = threadIdx.x;

  // static block ownership (same every round): decode once into registers
  int k1a = -1, k2a = -1, k1b = -1, k2b = -1;
  {
    int b = tid;
    if (b < NB) {
      int k1 = 0, rem = b;
      while (rem >= NP - k1) { rem -= NP - k1; ++k1; }
      k1a = k1; k2a = k1 + rem;
    }
    b = tid + NTH;
    if (b < NB) {
      int k1 = 0, rem = b;
      while (rem >= NP - k1) { rem -= NP - k1; ++k1; }
      k1b = k1; k2b = k1 + rem;
    }
  }

  // build A in LDS directly; W = I
  for (int idx = tid; idx < N * N; idx += NTH) {
    int i = idx / N, j = idx - i * N;
    float v;
    if (SPATIAL) {
      float dx0 = (c0[i*3+0] - c0[j*3+0]) * ia;
      float dx1 = (c0[i*3+1] - c0[j*3+1]) * ia;
      float dz  = (c0[i*3+2] - c0[j*3+2]) * ib;
      v = expf(-(dx0*dx0 + dx1*dx1)) * expf(-(dz*dz));
    } else {
      float d = (c1[i] - c1[j]) * ia;
      v = expf(-d*d);
    }
    if (i == j) v += JITTER;
    A[i * SA + j] = v;
    if (j < SW) W[i * SW + j] = (i == j) ? 1.0f : 0.0f;
  }
  __syncthreads();

  for (int sw = 0; sw < SWEEPS; ++sw) {
    for (int r = 0; r < N - 1; ++r) {
      // ---- phase 1: rotation params (round-robin tournament) ----
      if (tid < NP) {
        int p, q;
        if (tid == 0) { p = N - 1; q = r; }
        else {
          p = r + tid;  if (p >= N - 1) p -= N - 1;
          q = r - tid;  if (q < 0)      q += N - 1;
        }
        if (p > q) { int t = p; p = q; q = t; }
        float apq = A[p * SA + q];
        float app = A[p * SA + p];
        float aqq = A[q * SA + q];
        float c, s;
        if (fabsf(apq) < 1e-36f) { c = 1.0f; s = 0.0f; }
        else {
          float theta = (aqq - app) / (2.0f * apq);
          float tt = 1.0f / (fabsf(theta) + sqrtf(1.0f + theta * theta));
          if (theta < 0.0f) tt = -tt;
          c = 1.0f / sqrtf(1.0f + tt * tt);
          s = tt * c;
        }
        par[tid] = make_float4(c, s, __int_as_float(p), __int_as_float(q));
      }
      __syncthreads();

      // ---- phase 2: 2x2 A-blocks + W row rotations (disjoint, race-free) ----
      // A item 0
      if (k1a >= 0) {
        float4 P1 = par[k1a], P2 = par[k2a];
        float c1 = P1.x, s1 = P1.y;
        int p1 = __float_as_int(P1.z), q1 = __float_as_int(P1.w);
        float c2 = P2.x, s2 = P2.y;
        int p2 = __float_as_int(P2.z), q2 = __float_as_int(P2.w);
        float m00 = A[p1*SA+p2], m01 = A[p1*SA+q2];
        float m10 = A[q1*SA+p2], m11 = A[q1*SA+q2];
        float t00 = c1*m00 - s1*m10, t01 = c1*m01 - s1*m11;
        float t10 = s1*m00 + c1*m10, t11 = s1*m01 + c1*m11;
        float n00 = c2*t00 - s2*t01, n01 = s2*t00 + c2*t01;
        float n10 = c2*t10 - s2*t11, n11 = s2*t10 + c2*t11;
        A[p1*SA+p2] = n00; A[p1*SA+q2] = n01;
        A[q1*SA+p2] = n10; A[q1*SA+q2] = n11;
        if (k1a != k2a) {
          A[p2*SA+p1] = n00; A[p2*SA+q1] = n10;
          A[q2*SA+p1] = n01; A[q2*SA+q1] = n11;
        }
      }
      // A item 1 (only when NB > NTH)
      if (NB > NTH && k1b >= 0) {
        float4 P1 = par[k1b], P2 = par[k2b];
        float c1 = P1.x, s1 = P1.y;
        int p1 = __float_as_int(P1.z), q1 = __float_as_int(P1.w);
        float c2 = P2.x, s2 = P2.y;
        int p2 = __float_as_int(P2.z), q2 = __float_as_int(P2.w);
        float m00 = A[p1*SA+p2], m01 = A[p1*SA+q2];
        float m10 = A[q1*SA+p2], m11 = A[q1*SA+q2];
        float t00 = c1*m00 - s1*m10, t01 = c1*m01 - s1*m11;
        float t10 = s1*m00 + c1*m10, t11 = s1*m01 + c1*m11;
        float n00 = c2*t00 - s2*t01, n01 = s2*t00 + c2*t01;
        float n10 = c2*t10 - s2*t11, n11 = s2*t10 + c2*t11;
        A[p1*SA+p2] = n00; A[p1*SA+q2] = n01;
        A[q1*SA+p2] = n10; A[q1*SA+q2] = n11;
        if (k1b != k2b) {
          A[p2*SA+p1] = n00; A[p2*SA+q1] = n10;
          A[q2*SA+p1] = n01; A[q2*SA+q1] = n11;
        }
      }
      // W item 0
      {
        int w = tid;
        if (w < NWI) {
          int k = w / NC, ch = w - k * NC;
          float4 P = par[k];
          int p = __float_as_int(P.z), q = __float_as_int(P.w);
          float4 wp = ((float4*)W)[p * NC + ch];
          float4 wq = ((float4*)W)[q * NC + ch];
          float4 r0, r1;
          r0.x = P.x*wp.x - P.y*wq.x;  r1.x = P.y*wp.x + P.x*wq.x;
          r0.y = P.x*wp.y - P.y*wq.y;  r1.y = P.y*wp.y + P.x*wq.y;
          r0.z = P.x*wp.z - P.y*wq.z;  r1.z = P.y*wp.z + P.x*wq.z;
          r0.w = P.x*wp.w - P.y*wq.w;  r1.w = P.y*wp.w + P.x*wq.w;
          ((float4*)W)[p * NC + ch] = r0;
          ((float4*)W)[q * NC + ch] = r1;
        }
      }
      // W item 1 (only when NWI > NTH)
      if (NWI > NTH) {
        int w = tid + NTH;
        if (w < NWI) {
          int k = w / NC, ch = w - k * NC;
          float4 P = par[k];
          int p = __float_as_int(P.z), q = __float_as_int(P.w);
          float4 wp = ((float4*)W)[p * NC + ch];
          float4 wq = ((float4*)W)[q * NC + ch];
          float4 r0, r1;
          r0.x = P.x*wp.x - P.y*wq.x;  r1.x = P.y*wp.x + P.x*wq.x;
          r0.y = P.x*wp.y - P.y*wq.y;  r1.y = P.y*wp.y + P.x*wq.y;
          r0.z = P.x*wp.z - P.y*wq.z;  r1.z = P.y*wp.z + P.x*wq.z;
          r0.w = P.x*wp.w - P.y*wq.w;  r1.w = P.y*wp.w + P.x*wq.w;
          ((float4*)W)[p * NC + ch] = r0;
          ((float4*)W)[q * NC + ch] = r1;
        }
      }
      __syncthreads();
    }
  }

  // output W = V^T (row-major), eigenvalues = diag(A)
  for (int idx = tid; idx < N * N; idx += NTH) {
    int i = idx / N, j = idx - i * N;
    Vout[idx] = W[i * SW + j];
  }
  for (int i = tid; i < N; i += NTH) wout[i] = A[i * SA + i];
}

__global__ void __launch_bounds__(1024) jacobi_kernel(
    const float* __restrict__ space, const float* __restrict__ timec,
    const float* __restrict__ l_ll, const float* __restrict__ l_el,
    const float* __restrict__ l_t,
    float* __restrict__ wS, float* __restrict__ VSo,
    float* __restrict__ wT, float* __restrict__ VTo)
{
  extern __shared__ float lds[];
  if (blockIdx.x == 0)
    jacobi_body<64, 6, 1>(space, nullptr, expf(-l_ll[0]), expf(-l_el[0]), wS, VSo, lds);
  else
    jacobi_body<100, 6, 0>(nullptr, timec, expf(-l_t[0]), 0.0f, wT, VTo, lds);
}

// ---- generic tiny GEMM: one thread per output ----
// tA: 0=A[m][k], 1=A[k][m], 2=a=1/(w1[m]*w2[k]+exp(*scal))
// tB: 0=B[k][n], 1=B[n][k]
// mode: 0=acc, 1=acc/(w1[m]*w2[n]+exp(*scal)), 3=exp(*scal)-acc,
//       4=write C=acc and C2=acc^2
__global__ void __launch_bounds__(256) gemm_k(
    const float* __restrict__ A, const float* __restrict__ B,
    float* __restrict__ C, float* __restrict__ C2,
    int M, int N, int K, int tA, int tB, int mode,
    const float* __restrict__ w1, const float* __restrict__ w2,
    const float* __restrict__ scal)
{
  int idx = blockIdx.x * blockDim.x + threadIdx.x;
  if (idx >= M * N) return;
  int m = idx / N, n = idx - m * N;
  float nv = (scal != nullptr) ? expf(scal[0]) : 0.0f;
  float acc = 0.0f;
  for (int k = 0; k < K; ++k) {
    float a;
    if (tA == 2)      a = 1.0f / (w1[m] * w2[k] + nv);
    else if (tA == 1) a = A[k * M + m];
    else              a = A[m * K + k];
    float b = tB ? B[n * K + k] : B[k * N + n];
    acc += a * b;
  }
  if (mode == 4) { C[idx] = acc; C2[idx] = acc * acc; return; }
  float out;
  if (mode == 1)      out = acc / (w1[m] * w2[n] + nv);
  else if (mode == 3) out = nv - acc;
  else                out = acc;
  C[idx] = out;
}

extern "C" void kernel_launch(void* const* d_in, const int* in_sizes, int n_in,
                              void* d_out, int out_size, void* d_ws, size_t ws_size,
                              hipStream_t stream) {
  const float* space  = (const float*)d_in[0];
  const float* timec  = (const float*)d_in[1];
  const float* stData = (const float*)d_in[2];
  const float* tspace = (const float*)d_in[3];
  const float* ttime  = (const float*)d_in[4];
  const float* l_ll   = (const float*)d_in[5];
  const float* l_el   = (const float*)d_in[6];
  const float* l_t    = (const float*)d_in[7];
  const float* l_nv   = (const float*)d_in[8];
  const float* l_sv   = (const float*)d_in[9];
  const float* bias   = (const float*)d_in[10];
  const float* gain   = (const float*)d_in[11];
  float* ws  = (float*)d_ws;
  float* out = (float*)d_out;

  // LDS for n=100 block: A 100*101 + W 100*104 + par 50*4 floats = 82800 B
  const int JAC_LDS = (100*101 + 100*104 + 50*4) * 4;
  hipFuncSetAttribute((const void*)jacobi_kernel,
                      hipFuncAttributeMaxDynamicSharedMemorySize, JAC_LDS);

  build2_kernel<<<(BUILD2_TOTAL + 255) / 256, 256, 0, stream>>>(
      space, timec, stData, tspace, ttime, l_ll, l_el, l_t, bias, gain, ws);

  jacobi_kernel<<<2, 1024, JAC_LDS, stream>>>(
      space, timec, l_ll, l_el, l_t,
      ws + OFF_EWS, ws + OFF_VS, ws + OFF_EWT, ws + OFF_VT);

  auto grid = [](int mn) { return dim3((mn + 255) / 256); };
  float* NUL = nullptr;

  // GS = Ks @ VS (VS^T stored -> tB=1), also W2 = GS^2      [64,64,64]
  gemm_k<<<grid(4096), 256, 0, stream>>>(ws + OFF_KS, ws + OFF_VS,
      ws + OFF_GS, ws + OFF_W2, 64, 64, 64, 0, 1, 4, NUL, NUL, NUL);
  // GT = Kt @ VT (VT^T stored -> tB=1), also U2 = GT^2      [100,100,100]
  gemm_k<<<grid(10000), 256, 0, stream>>>(ws + OFF_KT, ws + OFF_VT,
      ws + OFF_GT, ws + OFF_U2, 100, 100, 100, 0, 1, 4, NUL, NUL, NUL);
  // P1 = VS^T @ Y (stored row-major -> tA=0)                [64,100,64]
  gemm_k<<<grid(6400), 256, 0, stream>>>(ws + OFF_VS, ws + OFF_Y,
      ws + OFF_P1, NUL, 64, 100, 64, 0, 0, 0, NUL, NUL, NUL);
  // tilde = (P1 @ VT) / (wS wT^T + s2)  (VT^T -> tB=1)      [64,100,100]
  gemm_k<<<grid(6400), 256, 0, stream>>>(ws + OFF_P1, ws + OFF_VT,
      ws + OFF_TILDE, NUL, 64, 100, 100, 0, 1, 1, ws + OFF_EWS, ws + OFF_EWT, l_nv);
  // Z = R @ U2^T, R[q][p]=1/(wS[q]wT[p]+s2)                 [64,100,100]
  gemm_k<<<grid(6400), 256, 0, stream>>>(NUL, ws + OFF_U2,
      ws + OFF_Z, NUL, 64, 100, 100, 2, 1, 0, ws + OFF_EWS, ws + OFF_EWT, l_nv);
  // M1 = GS @ tilde                                         [64,100,64]
  gemm_k<<<grid(6400), 256, 0, stream>>>(ws + OFF_GS, ws + OFF_TILDE,
      ws + OFF_M1, NUL, 64, 100, 64, 0, 0, 0, NUL, NUL, NUL);
  // yPred = M1 @ GT^T -> out[0:6400]                        [64,100,100]
  gemm_k<<<grid(6400), 256, 0, stream>>>(ws + OFF_M1, ws + OFF_GT,
      out, NUL, 64, 100, 100, 0, 1, 0, NUL, NUL, NUL);
  // yVar = exp(lsv) - W2 @ Z -> out[6400:]                  [64,100,64]
  gemm_k<<<grid(6400), 256, 0, stream>>>(ws + OFF_W2, ws + OFF_Z,
      out + 6400, NUL, 64, 100, 64, 0, 0, 3, NUL, NUL, l_sv);
}